// Round 3
// baseline (31574.228 us; speedup 1.0000x reference)
//
#include <hip/hip_runtime.h>
#include <stdint.h>

typedef unsigned short u16;
typedef unsigned int   u32;
typedef _Float16 half8 __attribute__((ext_vector_type(8)));
typedef __attribute__((ext_vector_type(4))) float f32x4;

#define DEV static __device__ __forceinline__

DEV float bf2f(u16 u){ union{u32 i; float f;} v; v.i=((u32)u)<<16; return v.f; }
DEV u16 f2bf(float f){ u32 x=__float_as_uint(f); return (u16)((x + 0x7FFFu + ((x>>16)&1u))>>16); }
DEV u16 f2hu(float f){ _Float16 h = (_Float16)f; return *(u16*)&h; }
DEV float hu2f(u16 u){ _Float16 h = *(_Float16*)&u; return (float)h; }
DEV float sigm(float x){ return 1.0f/(1.0f+__expf(-x)); }
DEV float tanhr(float x){ float a=fabsf(x); float e=__expf(-2.0f*a); float t=(1.0f-e)/(1.0f+e); return x<0.0f? -t:t; }

typedef const __attribute__((address_space(1))) u32 gu32;
typedef __attribute__((address_space(3))) u32 lu32;
DEV void gload16(const void* g, void* l){
  __builtin_amdgcn_global_load_lds((gu32*)g, (lu32*)l, 16, 0, 0);
}

// storage element (fp16 bits) from input (f32 or bf16 per flag)
DEV u16 ld_h(const void* p, size_t i, int isbf){
  float f = isbf ? bf2f(((const u16*)p)[i]) : ((const float*)p)[i];
  return f2hu(f);
}

// -------- dtype detector (see r1 notes): bf16 exponent-band statistics --------
__global__ void detect_dtype(const void* emb, u32* flag)
{
  const u16* p = (const u16*)emb;
  int i = threadIdx.x;
  u32 e0 = (p[i]    >> 7) & 0xFF;
  u32 e1 = (p[i+64] >> 7) & 0xFF;
  unsigned long long b0 = __ballot(e0 >= 0x60 && e0 <= 0x7E);
  unsigned long long b1 = __ballot(e1 >= 0x60 && e1 <= 0x7E);
  if (i == 0) *flag = (__popcll(b0) + __popcll(b1) > 96) ? 1u : 0u;
}

// ---------------- embedding gather: x0[t*64+b][e] = emb[tok[b][t]][e] (fp16 out) ----------------
__global__ __launch_bounds__(256) void embed_kernel(const int* __restrict__ tok,
                                                    const void* __restrict__ emb,
                                                    u16* __restrict__ x0,
                                                    const u32* __restrict__ flag)
{
  const int isbf = *flag;
  int idx = blockIdx.x*256 + threadIdx.x;   // 4 elements per thread
  int r = idx >> 6;                         // row = t*64+b
  int c = (idx & 63) << 2;
  int t = r >> 6, b = r & 63;
  int token = tok[b*1024 + t];
  u16 o[4];
  if (isbf){
    const u16* s = (const u16*)emb + (size_t)token*256 + c;
    #pragma unroll
    for (int j=0;j<4;++j) o[j] = f2hu(bf2f(s[j]));
  } else {
    float4 v = *(const float4*)((const float*)emb + (size_t)token*256 + c);
    o[0]=f2hu(v.x); o[1]=f2hu(v.y); o[2]=f2hu(v.z); o[3]=f2hu(v.w);
  }
  *(uint2*)(x0 + (size_t)r*256 + c) = *(uint2*)o;
}

// ------------- weight transpose (+ gate interleave): out[n'][k] = fp16(in[k][n]) -------------
__global__ __launch_bounds__(256) void transpose_bt(const void* __restrict__ in,
                                                    u16* __restrict__ out,
                                                    int K, int N, int perm,
                                                    const u32* __restrict__ flag)
{
  const int isbf = *flag;
  __shared__ u16 t[32][33];
  int nb = blockIdx.x*32, kb = blockIdx.y*32;
  int tx = threadIdx.x & 31, ty = threadIdx.x >> 5;   // 32 x 8
  #pragma unroll
  for (int i=0;i<4;++i){
    int kl = ty + i*8;
    t[kl][tx] = ld_h(in, (size_t)(kb+kl)*N + nb + tx, isbf);
  }
  __syncthreads();
  #pragma unroll
  for (int i=0;i<4;++i){
    int nl = ty + i*8;
    int n = nb + nl;
    int np = perm ? ((n & 511)*4 + (n >> 9)) : n;
    out[(size_t)np*K + kb + tx] = t[tx][nl];
  }
}

__global__ __launch_bounds__(256) void bias_prep(const void* __restrict__ in, float* __restrict__ out,
                                                 int N, int perm, const u32* __restrict__ flag)
{
  const int isbf = *flag;
  int n = blockIdx.x*256 + threadIdx.x;
  if (n < N){
    int np = perm ? ((n & 511)*4 + (n >> 9)) : n;
    out[np] = isbf ? bf2f(((const u16*)in)[n]) : ((const float*)in)[n];
  }
}

// ---------------- fp16 GEMM: C[M][N] = A[M][K] @ BT[N][K]^T + bias ----------------
// 128x128 tile, 4 waves (2x2), BK=32, 16x16x32 f16 MFMA, global_load_lds staging.
__global__ __launch_bounds__(256) void gemm_bt(const u16* __restrict__ A, const u16* __restrict__ BT,
                                               const float* __restrict__ bias, void* __restrict__ C,
                                               int M, int N, int K, int permute,
                                               int finalout, const u32* __restrict__ flag)
{
  __shared__ u16 As[128*32];
  __shared__ u16 Bs[128*32];
  const int tid = threadIdx.x, lane = tid & 63, wid = tid >> 6;
  const int wr = wid >> 1, wc = wid & 1;
  const int m0 = blockIdx.x*128, n0 = blockIdx.y*128;
  const int r  = tid >> 2;
  const int ce = (tid & 3)*8;
  const u16* a0 = A  + (size_t)(m0 + r)*K + ce;
  const u16* a1 = A  + (size_t)(m0 + 64 + r)*K + ce;
  const u16* b0 = BT + (size_t)(n0 + r)*K + ce;
  const u16* b1 = BT + (size_t)(n0 + 64 + r)*K + ce;
  char* asw0 = (char*)As + (wid<<10);
  char* asw1 = (char*)As + 4096 + (wid<<10);
  char* bsw0 = (char*)Bs + (wid<<10);
  char* bsw1 = (char*)Bs + 4096 + (wid<<10);

  f32x4 acc[4][4];
  #pragma unroll
  for (int i=0;i<4;++i)
    #pragma unroll
    for (int j=0;j<4;++j) acc[i][j] = (f32x4){0.f,0.f,0.f,0.f};

  const int koff = (lane>>4)*8;
  for (int k0 = 0; k0 < K; k0 += 32){
    __syncthreads();
    gload16(a0 + k0, asw0);
    gload16(a1 + k0, asw1);
    gload16(b0 + k0, bsw0);
    gload16(b1 + k0, bsw1);
    __syncthreads();
    half8 af[4], bf[4];
    #pragma unroll
    for (int mt=0;mt<4;++mt) af[mt] = *(const half8*)(As + (wr*64 + mt*16 + (lane&15))*32 + koff);
    #pragma unroll
    for (int nt=0;nt<4;++nt) bf[nt] = *(const half8*)(Bs + (wc*64 + nt*16 + (lane&15))*32 + koff);
    #pragma unroll
    for (int mt=0;mt<4;++mt)
      #pragma unroll
      for (int nt=0;nt<4;++nt)
        acc[mt][nt] = __builtin_amdgcn_mfma_f32_16x16x32_f16(af[mt], bf[nt], acc[mt][nt], 0,0,0);
  }
  const int wrf32 = finalout && (*flag == 0);
  #pragma unroll
  for (int mt=0;mt<4;++mt){
    #pragma unroll
    for (int nt=0;nt<4;++nt){
      int col = n0 + wc*64 + nt*16 + (lane&15);
      float bv = bias ? bias[col] : 0.f;
      #pragma unroll
      for (int j=0;j<4;++j){
        int row = m0 + wr*64 + mt*16 + ((lane>>4)<<2) + j;
        int orow = permute ? (((row & 63) << 10) | (row >> 6)) : row;
        float v = acc[mt][nt][j] + bv;
        if (finalout){
          if (wrf32) ((float*)C)[(size_t)orow*N + col] = v;
          else       ((u16*)C)[(size_t)orow*N + col] = f2bf(v);
        } else {
          ((u16*)C)[(size_t)orow*N + col] = f2hu(v);
        }
      }
    }
  }
}

// ---------------- recurrence: 32 WGs, each owns u-slice of 16 (64 interleaved n'-cols) ----------------
#define NWG 32
__global__ __launch_bounds__(256,1) void lstm_step(const u16* __restrict__ Zx,   // [128*64][2048] fp16
                                                   const u16* __restrict__ WrT,  // [2048][512] fp16
                                                   const int* __restrict__ lengths,
                                                   u16* __restrict__ xout,       // [65536][512] fp16
                                                   u16* H0, u16* H1,             // [64][512] fp16
                                                   float* __restrict__ Cg,       // [64][512] f32
                                                   u32* flags,
                                                   int t0, int nsteps)
{
  extern __shared__ char smem[];
  u16*  Hs = (u16*)smem;             // 65536 B  (row-swizzled)
  float* Zs = (float*)(smem+65536);  // 16384 B
  float* Cs = (float*)(smem+81920);  //  4096 B

  const int tid = threadIdx.x, lane = tid & 63, w = tid >> 6;
  const int wg = blockIdx.x;
  const int koff = (lane>>4)*8;

  half8 breg[4][16];
  #pragma unroll
  for (int nt=0;nt<4;++nt)
    #pragma unroll
    for (int kk=0;kk<16;++kk)
      breg[nt][kk] = *(const half8*)(WrT + (size_t)(wg*64 + nt*16 + (lane&15))*512 + kk*32 + koff);

  #pragma unroll
  for (int i=0;i<4;++i){ int idx = tid*4+i; Cs[idx] = Cg[(size_t)(idx>>4)*512 + wg*16 + (idx&15)]; }
  __syncthreads();

  const u16* Hc = H0; u16* Hn = H1;
  const int gb = tid >> 2;
  const int gu0 = (tid & 3) * 4;
  const int mylen = lengths[gb];

  for (int lt = 0; lt < nsteps; ++lt){
    const int t = t0 + lt;
    #pragma unroll
    for (int i=0;i<16;++i){
      int row = i*4 + (tid>>6);
      int blk = tid & 63;
      gload16((const char*)Hc + row*1024 + ((blk ^ (row & 7)) << 4),
              (char*)Hs + i*4096 + (w<<10));
    }
    __syncthreads();

    f32x4 acc[4];
    #pragma unroll
    for (int i=0;i<4;++i) acc[i] = (f32x4){0.f,0.f,0.f,0.f};
    {
      const int arow = w*16 + (lane&15);
      const int sw = (arow & 7) << 4;
      #pragma unroll
      for (int kk=0;kk<16;++kk){
        int kbyte = (kk*32 + koff)*2;
        half8 afr = *(const half8*)((char*)Hs + arow*1024 + (kbyte ^ sw));
        #pragma unroll
        for (int nt=0;nt<4;++nt)
          acc[nt] = __builtin_amdgcn_mfma_f32_16x16x32_f16(afr, breg[nt][kk], acc[nt], 0,0,0);
      }
    }
    #pragma unroll
    for (int nt=0;nt<4;++nt)
      #pragma unroll
      for (int j=0;j<4;++j)
        Zs[(w*16 + ((lane>>4)<<2) + j)*64 + nt*16 + (lane&15)] = acc[nt][j];
    __syncthreads();

    const u16* zrow = Zx + ((size_t)lt*64 + gb)*2048 + wg*64 + gu0*4;
    uint4 q0 = *(const uint4*)zrow;
    uint4 q1 = *(const uint4*)(zrow + 8);
    u16 zx[16];
    *(uint4*)(zx) = q0; *(uint4*)(zx+8) = q1;
    const bool live = t < mylen;
    u16 ov4[4], hv4[4];
    #pragma unroll
    for (int uu=0;uu<4;++uu){
      const int ul = gu0 + uu;
      float4 zv = *(const float4*)&Zs[gb*64 + ul*4];
      float zi = zv.x + hu2f(zx[uu*4+0]);
      float zf = zv.y + hu2f(zx[uu*4+1]);
      float zg = zv.z + hu2f(zx[uu*4+2]);
      float zo = zv.w + hu2f(zx[uu*4+3]);
      float ii = sigm(zi), ff = sigm(zf), gg = tanhr(zg), oo = sigm(zo);
      float cold = Cs[gb*16 + ul];
      float cnew = ff*cold + ii*gg;
      float hnew = oo * tanhr(cnew);
      Cs[gb*16 + ul] = live ? cnew : cold;
      int kb2 = (wg*16 + ul)*2;
      float hold = hu2f(*(const u16*)((char*)Hs + gb*1024 + (kb2 ^ ((gb & 7) << 4))));
      ov4[uu] = f2hu(live ? hnew : 0.f);
      hv4[uu] = f2hu(live ? hnew : hold);
    }
    *(uint2*)(xout + ((size_t)t*64 + gb)*512 + wg*16 + gu0) = *(uint2*)ov4;
    *(uint2*)(Hn + (size_t)gb*512 + wg*16 + gu0) = *(uint2*)hv4;

    __threadfence();
    __syncthreads();
    if (w == 0){
      if (lane == 0)
        __hip_atomic_store(&flags[wg*16], (u32)(t+1), __ATOMIC_RELEASE, __HIP_MEMORY_SCOPE_AGENT);
      if (lane < NWG){
        while (__hip_atomic_load(&flags[lane*16], __ATOMIC_ACQUIRE, __HIP_MEMORY_SCOPE_AGENT) < (u32)(t+1))
          __builtin_amdgcn_s_sleep(2);
      }
    }
    __syncthreads();
    const u16* tmp = Hc; Hc = Hn; Hn = (u16*)tmp;
  }
  __syncthreads();
  #pragma unroll
  for (int i=0;i<4;++i){ int idx = tid*4+i; Cg[(size_t)(idx>>4)*512 + wg*16 + (idx&15)] = Cs[idx]; }
}

// ---------------------------------- host ----------------------------------
extern "C" void kernel_launch(void* const* d_in, const int* in_sizes, int n_in,
                              void* d_out, int out_size, void* d_ws, size_t ws_size,
                              hipStream_t stream)
{
  const int* tokens  = (const int*)d_in[0];
  const int* lengths = (const int*)d_in[1];
  const void* emb    = d_in[2];
  const void* Wk[3] = {d_in[3], d_in[6], d_in[9]};
  const void* Wr[3] = {d_in[4], d_in[7], d_in[10]};
  const void* bv[3] = {d_in[5], d_in[8], d_in[11]};
  const void* Wd = d_in[12];
  const void* bd = d_in[13];

  char* ws = (char*)d_ws;
  u16* Zx = (u16*)(ws + 0);               // 32MB (T-chunk of 128 steps)
  u16* xA = (u16*)(ws + 33554432);        // 64MB
  u16* xB = (u16*)(ws + 100663296);       // 64MB ; x0 aliases its head
  u16* x0 = xB;
  size_t o = 167772160;
  u16 *WkT[3], *WrT[3];
  WkT[0] = (u16*)(ws+o); o += 2048ull*256*2;
  WkT[1] = (u16*)(ws+o); o += 2048ull*512*2;
  WkT[2] = (u16*)(ws+o); o += 2048ull*512*2;
  for (int l=0;l<3;++l){ WrT[l] = (u16*)(ws+o); o += 2048ull*512*2; }
  u16* WdT = (u16*)(ws+o); o += 512ull*512*2;
  float* biasP[3];
  for (int l=0;l<3;++l){ biasP[l] = (float*)(ws+o); o += 2048*4; }
  float* bdP = (float*)(ws+o); o += 512*4;
  size_t ctrl0 = o;
  u16* Hb[3][2]; float* Cg[3];
  for (int l=0;l<3;++l){ Hb[l][0] = (u16*)(ws+o); o += 65536; Hb[l][1] = (u16*)(ws+o); o += 65536; }
  for (int l=0;l<3;++l){ Cg[l] = (float*)(ws+o); o += 131072; }
  u32* flagbase = (u32*)(ws+o); o += 3*512*4;
  u32* dtypeflag = (u32*)(ws+o); o += 256;
  size_t need = o;
  if (ws_size < need) return;

  hipMemsetAsync(ws + ctrl0, 0, need - ctrl0, stream);
  hipFuncSetAttribute(reinterpret_cast<const void*>(lstm_step),
                      hipFuncAttributeMaxDynamicSharedMemorySize, 86016);

  detect_dtype<<<1,64,0,stream>>>(emb, dtypeflag);
  embed_kernel<<<16384,256,0,stream>>>(tokens, emb, x0, dtypeflag);
  transpose_bt<<<dim3(64,8) ,256,0,stream>>>(Wk[0], WkT[0], 256, 2048, 1, dtypeflag);
  transpose_bt<<<dim3(64,16),256,0,stream>>>(Wk[1], WkT[1], 512, 2048, 1, dtypeflag);
  transpose_bt<<<dim3(64,16),256,0,stream>>>(Wk[2], WkT[2], 512, 2048, 1, dtypeflag);
  for (int l=0;l<3;++l)
    transpose_bt<<<dim3(64,16),256,0,stream>>>(Wr[l], WrT[l], 512, 2048, 1, dtypeflag);
  transpose_bt<<<dim3(16,16),256,0,stream>>>(Wd, WdT, 512, 512, 0, dtypeflag);
  for (int l=0;l<3;++l) bias_prep<<<8,256,0,stream>>>(bv[l], biasP[l], 2048, 1, dtypeflag);
  bias_prep<<<2,256,0,stream>>>(bd, bdP, 512, 0, dtypeflag);

  const u16* xin = x0; int K = 256;
  for (int l=0;l<3;++l){
    u16* xo = (l==0) ? xA : (l==1 ? xB : xA);
    u32* fl = flagbase + l*512;
    for (int c=0;c<8;++c){
      gemm_bt<<<dim3(64,16),256,0,stream>>>(xin + (size_t)c*8192*K, WkT[l], biasP[l], Zx,
                                            8192, 2048, K, 0, 0, dtypeflag);
      lstm_step<<<dim3(NWG),256,86016,stream>>>(Zx, WrT[l], lengths, xo,
                                                Hb[l][0], Hb[l][1], Cg[l], fl, c*128, 128);
    }
    xin = xo; K = 512;
  }
  gemm_bt<<<dim3(512,4),256,0,stream>>>(xin, WdT, bdP, d_out, 65536, 512, 512, 1, 1, dtypeflag);
}

// Round 4
// 11427.558 us; speedup vs baseline: 2.7630x; 2.7630x over previous
//
#include <hip/hip_runtime.h>
#include <stdint.h>

typedef unsigned short u16;
typedef unsigned int   u32;
typedef unsigned long long u64;
typedef _Float16 half8 __attribute__((ext_vector_type(8)));
typedef __attribute__((ext_vector_type(4))) float f32x4;

#define DEV static __device__ __forceinline__

DEV float bf2f(u16 u){ union{u32 i; float f;} v; v.i=((u32)u)<<16; return v.f; }
DEV u16 f2bf(float f){ u32 x=__float_as_uint(f); return (u16)((x + 0x7FFFu + ((x>>16)&1u))>>16); }
DEV u16 f2hu(float f){ _Float16 h = (_Float16)f; return *(u16*)&h; }
DEV float hu2f(u16 u){ _Float16 h = *(_Float16*)&u; return (float)h; }
DEV float sigm(float x){ return 1.0f/(1.0f+__expf(-x)); }
DEV float tanhr(float x){ float a=fabsf(x); float e=__expf(-2.0f*a); float t=(1.0f-e)/(1.0f+e); return x<0.0f? -t:t; }

typedef const __attribute__((address_space(1))) u32 gu32;
typedef __attribute__((address_space(3))) u32 lu32;
DEV void gload16(const void* g, void* l){
  __builtin_amdgcn_global_load_lds((gu32*)g, (lu32*)l, 16, 0, 0);
}

DEV u16 ld_h(const void* p, size_t i, int isbf){
  float f = isbf ? bf2f(((const u16*)p)[i]) : ((const float*)p)[i];
  return f2hu(f);
}

// -------- dtype detector: bf16 exponent-band statistics --------
__global__ void detect_dtype(const void* emb, u32* flag)
{
  const u16* p = (const u16*)emb;
  int i = threadIdx.x;
  u32 e0 = (p[i]    >> 7) & 0xFF;
  u32 e1 = (p[i+64] >> 7) & 0xFF;
  unsigned long long b0 = __ballot(e0 >= 0x60 && e0 <= 0x7E);
  unsigned long long b1 = __ballot(e1 >= 0x60 && e1 <= 0x7E);
  if (i == 0) *flag = (__popcll(b0) + __popcll(b1) > 96) ? 1u : 0u;
}

// -------- emb table -> fp16 (512x256) --------
__global__ __launch_bounds__(256) void embconv(const void* __restrict__ emb, u16* __restrict__ embH,
                                               const u32* __restrict__ flag)
{
  const int isbf = *flag;
  int i = blockIdx.x*256 + threadIdx.x;     // 131072 elements
  embH[i] = ld_h(emb, i, isbf);
}

// ------------- weight transpose (+ gate interleave): out[n'][k] = fp16(in[k][n]) -------------
__global__ __launch_bounds__(256) void transpose_bt(const void* __restrict__ in,
                                                    u16* __restrict__ out,
                                                    int K, int N, int perm,
                                                    const u32* __restrict__ flag)
{
  const int isbf = *flag;
  __shared__ u16 t[32][33];
  int nb = blockIdx.x*32, kb = blockIdx.y*32;
  int tx = threadIdx.x & 31, ty = threadIdx.x >> 5;   // 32 x 8
  #pragma unroll
  for (int i=0;i<4;++i){
    int kl = ty + i*8;
    t[kl][tx] = ld_h(in, (size_t)(kb+kl)*N + nb + tx, isbf);
  }
  __syncthreads();
  #pragma unroll
  for (int i=0;i<4;++i){
    int nl = ty + i*8;
    int n = nb + nl;
    int np = perm ? ((n & 511)*4 + (n >> 9)) : n;
    out[(size_t)np*K + kb + tx] = t[tx][nl];
  }
}

__global__ __launch_bounds__(256) void bias_prep(const void* __restrict__ in, float* __restrict__ out,
                                                 int N, int perm, const u32* __restrict__ flag)
{
  const int isbf = *flag;
  int n = blockIdx.x*256 + threadIdx.x;
  if (n < N){
    int np = perm ? ((n & 511)*4 + (n >> 9)) : n;
    out[np] = isbf ? bf2f(((const u16*)in)[n]) : ((const float*)in)[n];
  }
}

// ---------------- batched chunk GEMM: up to 3 chunk GEMMs (z = layer), M=4096, N=2048 ----------------
// z=0: A gathered from embH via tokens (K=256). z=1,2: A = xo_prev chunk (K=512). fp16 out + bias.
__global__ __launch_bounds__(256) void gemm3(
    const u16* __restrict__ A1, const u16* __restrict__ A2,
    const u16* __restrict__ BT0, const u16* __restrict__ BT1, const u16* __restrict__ BT2,
    const float* __restrict__ b0p, const float* __restrict__ b1p, const float* __restrict__ b2p,
    u16* __restrict__ C0, u16* __restrict__ C1, u16* __restrict__ C2,
    const int* __restrict__ tok, const u16* __restrict__ embH, int t0g,
    int act0, int act1, int act2)
{
  const int z = blockIdx.z;
  if (z==0 && !act0) return;
  if (z==1 && !act1) return;
  if (z==2 && !act2) return;
  const int K = (z==0) ? 256 : 512;
  const u16* BT = z==0?BT0 : z==1?BT1 : BT2;
  const float* bias = z==0?b0p : z==1?b1p : b2p;
  u16* C = z==0?C0 : z==1?C1 : C2;

  __shared__ u16 As[128*32];
  __shared__ u16 Bs[128*32];
  const int tid = threadIdx.x, lane = tid & 63, wid = tid >> 6;
  const int wr = wid >> 1, wc = wid & 1;
  const int m0 = blockIdx.x*128, n0 = blockIdx.y*128;
  const int r  = tid >> 2;
  const int ce = (tid & 3)*8;
  const u16 *a0, *a1;
  if (z == 0){
    int r0 = m0 + r;     int tt = t0g + (r0>>6); int bb = r0 & 63;
    a0 = embH + (size_t)tok[bb*1024 + tt]*256 + ce;
    int r1 = m0 + 64 + r; tt = t0g + (r1>>6); bb = r1 & 63;
    a1 = embH + (size_t)tok[bb*1024 + tt]*256 + ce;
  } else {
    const u16* A = (z==1) ? A1 : A2;
    a0 = A + (size_t)(m0 + r)*512 + ce;
    a1 = A + (size_t)(m0 + 64 + r)*512 + ce;
  }
  const u16* bp0 = BT + (size_t)(n0 + r)*K + ce;
  const u16* bp1 = BT + (size_t)(n0 + 64 + r)*K + ce;
  char* asw0 = (char*)As + (wid<<10);
  char* asw1 = (char*)As + 4096 + (wid<<10);
  char* bsw0 = (char*)Bs + (wid<<10);
  char* bsw1 = (char*)Bs + 4096 + (wid<<10);

  f32x4 acc[4][4];
  #pragma unroll
  for (int i=0;i<4;++i)
    #pragma unroll
    for (int j=0;j<4;++j) acc[i][j] = (f32x4){0.f,0.f,0.f,0.f};

  const int koff = (lane>>4)*8;
  for (int k0 = 0; k0 < K; k0 += 32){
    __syncthreads();
    gload16(a0 + k0, asw0);
    gload16(a1 + k0, asw1);
    gload16(bp0 + k0, bsw0);
    gload16(bp1 + k0, bsw1);
    __syncthreads();
    half8 af[4], bf[4];
    #pragma unroll
    for (int mt=0;mt<4;++mt) af[mt] = *(const half8*)(As + (wr*64 + mt*16 + (lane&15))*32 + koff);
    #pragma unroll
    for (int nt=0;nt<4;++nt) bf[nt] = *(const half8*)(Bs + (wc*64 + nt*16 + (lane&15))*32 + koff);
    #pragma unroll
    for (int mt=0;mt<4;++mt)
      #pragma unroll
      for (int nt=0;nt<4;++nt)
        acc[mt][nt] = __builtin_amdgcn_mfma_f32_16x16x32_f16(af[mt], bf[nt], acc[mt][nt], 0,0,0);
  }
  #pragma unroll
  for (int mt=0;mt<4;++mt){
    #pragma unroll
    for (int nt=0;nt<4;++nt){
      int col = n0 + wc*64 + nt*16 + (lane&15);
      float bv = bias[col];
      #pragma unroll
      for (int j=0;j<4;++j){
        int row = m0 + wr*64 + mt*16 + ((lane>>4)<<2) + j;
        C[(size_t)row*2048 + col] = f2hu(acc[mt][nt][j] + bv);
      }
    }
  }
}

// ---------------- final logits GEMM (K=512, output permute t-major -> (B,T), dtype per flag) --------
__global__ __launch_bounds__(256) void gemm_bt(const u16* __restrict__ A, const u16* __restrict__ BT,
                                               const float* __restrict__ bias, void* __restrict__ C,
                                               int M, int N, int K, const u32* __restrict__ flag)
{
  __shared__ u16 As[128*32];
  __shared__ u16 Bs[128*32];
  const int tid = threadIdx.x, lane = tid & 63, wid = tid >> 6;
  const int wr = wid >> 1, wc = wid & 1;
  const int m0 = blockIdx.x*128, n0 = blockIdx.y*128;
  const int r  = tid >> 2;
  const int ce = (tid & 3)*8;
  const u16* a0 = A  + (size_t)(m0 + r)*K + ce;
  const u16* a1 = A  + (size_t)(m0 + 64 + r)*K + ce;
  const u16* b0 = BT + (size_t)(n0 + r)*K + ce;
  const u16* b1 = BT + (size_t)(n0 + 64 + r)*K + ce;
  char* asw0 = (char*)As + (wid<<10);
  char* asw1 = (char*)As + 4096 + (wid<<10);
  char* bsw0 = (char*)Bs + (wid<<10);
  char* bsw1 = (char*)Bs + 4096 + (wid<<10);

  f32x4 acc[4][4];
  #pragma unroll
  for (int i=0;i<4;++i)
    #pragma unroll
    for (int j=0;j<4;++j) acc[i][j] = (f32x4){0.f,0.f,0.f,0.f};

  const int koff = (lane>>4)*8;
  for (int k0 = 0; k0 < K; k0 += 32){
    __syncthreads();
    gload16(a0 + k0, asw0);
    gload16(a1 + k0, asw1);
    gload16(b0 + k0, bsw0);
    gload16(b1 + k0, bsw1);
    __syncthreads();
    half8 af[4], bf[4];
    #pragma unroll
    for (int mt=0;mt<4;++mt) af[mt] = *(const half8*)(As + (wr*64 + mt*16 + (lane&15))*32 + koff);
    #pragma unroll
    for (int nt=0;nt<4;++nt) bf[nt] = *(const half8*)(Bs + (wc*64 + nt*16 + (lane&15))*32 + koff);
    #pragma unroll
    for (int mt=0;mt<4;++mt)
      #pragma unroll
      for (int nt=0;nt<4;++nt)
        acc[mt][nt] = __builtin_amdgcn_mfma_f32_16x16x32_f16(af[mt], bf[nt], acc[mt][nt], 0,0,0);
  }
  const int wrf32 = (*flag == 0);
  #pragma unroll
  for (int mt=0;mt<4;++mt){
    #pragma unroll
    for (int nt=0;nt<4;++nt){
      int col = n0 + wc*64 + nt*16 + (lane&15);
      float bv = bias[col];
      #pragma unroll
      for (int j=0;j<4;++j){
        int row = m0 + wr*64 + mt*16 + ((lane>>4)<<2) + j;
        int orow = ((row & 63) << 10) | (row >> 6);
        float v = acc[mt][nt][j] + bv;
        if (wrf32) ((float*)C)[(size_t)orow*N + col] = v;
        else       ((u16*)C)[(size_t)orow*N + col] = f2bf(v);
      }
    }
  }
}

// ---------------- fused pipelined recurrence: 96 WGs = 3 layers x 32 WGs ----------------
// Dispatch d: layer l processes chunk c = d-l (64 steps) if 0<=c<16.
// Per layer-group: u-slice split (WG owns 64 interleaved gate-cols = 16 u's).
// Wr slice in LDS (swizzled). H exchange via RELAXED AGENT 8B atomics (sc-bit path,
// no L2 writeback/invalidate). Flags contiguous 4B, coalesced 32-lane poll.
#define NWG 32
__global__ __launch_bounds__(256,1) void lstm3(
    const u16* __restrict__ Zx0, const u16* __restrict__ Zx1, const u16* __restrict__ Zx2,
    const u16* __restrict__ Wr0T, const u16* __restrict__ Wr1T, const u16* __restrict__ Wr2T,
    const int* __restrict__ lengths,
    u16* __restrict__ xo0, u16* __restrict__ xo1, u16* __restrict__ xf,
    u16* Hbase, float* Cbase, u32* flagbase, int d)
{
  extern __shared__ char smem[];
  u16*  Hs  = (u16*)smem;              // 64KB, row-swizzled
  u16*  WrL = (u16*)(smem + 65536);    // 64KB, row-swizzled
  float* Zs = (float*)(smem + 131072); // 16KB

  const int tid = threadIdx.x, lane = tid & 63, w = tid >> 6;
  const int layer = blockIdx.x >> 5, wg = blockIdx.x & 31;
  const int c = d - layer;
  if (c < 0 || c > 15) return;
  const int t0 = c * 64;

  const u16* Zx  = layer==0 ? Zx0 : layer==1 ? Zx1 : Zx2;
  const u16* WrT = layer==0 ? Wr0T : layer==1 ? Wr1T : Wr2T;
  u16* H0 = Hbase + (size_t)layer*65536;     // 2 buffers x 32768 u16
  u16* H1 = H0 + 32768;
  float* CgL = Cbase + (size_t)layer*32768;
  u32* flags = flagbase + layer*32;

  // ---- stage Wr slice into LDS once: row cc (local gate-col), swizzled 16B blocks ----
  {
    int cc = tid >> 2, q = tid & 3;
    const u16* src = WrT + (size_t)(wg*64 + cc)*512 + q*128;
    char* db = (char*)WrL + cc*1024;
    int sw = (cc & 7) << 4;
    #pragma unroll
    for (int j=0;j<16;++j){
      int kblk = q*16 + j;
      uint4 v = *(const uint4*)(src + j*8);
      *(uint4*)(db + ((kblk<<4) ^ sw)) = v;
    }
  }

  const int gb = tid >> 2;              // batch handled in gates phase
  const int gu0 = (tid & 3) * 4;        // first of 4 local u's
  const int mylen = lengths[gb];
  float cst[4];
  #pragma unroll
  for (int uu=0;uu<4;++uu) cst[uu] = CgL[gb*512 + wg*16 + gu0 + uu];

  __syncthreads();

  u16* Hc = H0; u16* Hn = H1;
  const int srow = tid >> 2, sq = tid & 3;        // H staging assignment
  const int arow = w*16 + (lane&15), asw = (arow & 7) << 4;
  const int koff2 = (lane>>4)*16;                 // byte offset inside 64B k-group
  int crow[4], csw[4];
  #pragma unroll
  for (int nt=0;nt<4;++nt){ crow[nt] = nt*16 + (lane&15); csw[nt] = (crow[nt] & 7) << 4; }

  for (int lt = 0; lt < 64; ++lt){
    const int t = t0 + lt;
    // prefetch Zx row (plain cached loads, written by earlier dispatch)
    const u16* zrow = Zx + ((size_t)lt*64 + gb)*2048 + wg*64 + gu0*4;
    uint4 zq0 = *(const uint4*)zrow;
    uint4 zq1 = *(const uint4*)(zrow + 8);

    // ---- stage H: coherent (agent-scope) 8B loads -> swizzled LDS ----
    {
      const u64* hsrc = (const u64*)(Hc + (size_t)srow*512) + sq*32;
      u64 hv[32];
      #pragma unroll
      for (int j=0;j<32;++j)
        hv[j] = __hip_atomic_load(hsrc + j, __ATOMIC_RELAXED, __HIP_MEMORY_SCOPE_AGENT);
      char* db = (char*)Hs + srow*1024;
      int sw = (srow & 7) << 4;
      #pragma unroll
      for (int j=0;j<16;++j){
        int kblk = sq*16 + j;
        uint4 v;
        v.x = (u32)hv[2*j];   v.y = (u32)(hv[2*j]>>32);
        v.z = (u32)hv[2*j+1]; v.w = (u32)(hv[2*j+1]>>32);
        *(uint4*)(db + ((kblk<<4) ^ sw)) = v;
      }
    }
    __syncthreads();

    // ---- z_h = H @ Wr-slice ----
    f32x4 acc[4];
    #pragma unroll
    for (int i=0;i<4;++i) acc[i] = (f32x4){0.f,0.f,0.f,0.f};
    #pragma unroll
    for (int kk=0;kk<16;++kk){
      int kb = kk*64 + koff2;
      half8 afr = *(const half8*)((char*)Hs + arow*1024 + (kb ^ asw));
      #pragma unroll
      for (int nt=0;nt<4;++nt){
        half8 bfr = *(const half8*)((char*)WrL + crow[nt]*1024 + (kb ^ csw[nt]));
        acc[nt] = __builtin_amdgcn_mfma_f32_16x16x32_f16(afr, bfr, acc[nt], 0,0,0);
      }
    }
    #pragma unroll
    for (int nt=0;nt<4;++nt)
      #pragma unroll
      for (int j=0;j<4;++j)
        Zs[(w*16 + ((lane>>4)<<2) + j)*64 + nt*16 + (lane&15)] = acc[nt][j];
    __syncthreads();

    // ---- gates ----
    u16 zx[16];
    *(uint4*)(zx) = zq0; *(uint4*)(zx+8) = zq1;
    const bool live = t < mylen;
    u16 ov4[4], hv4[4];
    #pragma unroll
    for (int uu=0;uu<4;++uu){
      const int ul = gu0 + uu;
      float4 zv = *(const float4*)&Zs[gb*64 + ul*4];
      float zi = zv.x + hu2f(zx[uu*4+0]);
      float zf = zv.y + hu2f(zx[uu*4+1]);
      float zg = zv.z + hu2f(zx[uu*4+2]);
      float zo = zv.w + hu2f(zx[uu*4+3]);
      float ii = sigm(zi), ff = sigm(zf), gg = tanhr(zg), oo = sigm(zo);
      float cold = cst[uu];
      float cnew = ff*cold + ii*gg;
      float hnew = oo * tanhr(cnew);
      cst[uu] = live ? cnew : cold;
      int kb2 = (wg*16 + ul)*2;
      float hold = hu2f(*(const u16*)((char*)Hs + gb*1024 + (kb2 ^ ((gb & 7) << 4))));
      ov4[uu] = f2hu(live ? hnew : 0.f);
      hv4[uu] = f2hu(live ? hnew : hold);
    }
    // xout (plain store, consumed next dispatch)
    if (layer == 2)
      *(uint2*)(xf + ((size_t)t*64 + gb)*512 + wg*16 + gu0) = *(uint2*)ov4;
    else {
      u16* xo = layer ? xo1 : xo0;
      *(uint2*)(xo + ((size_t)lt*64 + gb)*512 + wg*16 + gu0) = *(uint2*)ov4;
    }
    // H next-state: agent-scope 8B store (write-through to coherence point)
    u64 hpack; *(uint2*)&hpack = *(uint2*)hv4;
    __hip_atomic_store((u64*)(Hn + (size_t)gb*512 + wg*16 + gu0), hpack,
                       __ATOMIC_RELAXED, __HIP_MEMORY_SCOPE_AGENT);
    asm volatile("s_waitcnt vmcnt(0)" ::: "memory");   // all our stores ack'd at coherence point
    __syncthreads();
    if (w == 0){
      if (lane == 0)
        __hip_atomic_store(&flags[wg], (u32)(t+1), __ATOMIC_RELAXED, __HIP_MEMORY_SCOPE_AGENT);
      if (lane < NWG){
        while (__hip_atomic_load(&flags[lane], __ATOMIC_RELAXED, __HIP_MEMORY_SCOPE_AGENT) < (u32)(t+1))
          __builtin_amdgcn_s_sleep(2);
      }
    }
    __syncthreads();
    u16* tmp = Hc; Hc = Hn; Hn = tmp;
  }

  #pragma unroll
  for (int uu=0;uu<4;++uu) CgL[gb*512 + wg*16 + gu0 + uu] = cst[uu];
}

// ---------------------------------- host ----------------------------------
extern "C" void kernel_launch(void* const* d_in, const int* in_sizes, int n_in,
                              void* d_out, int out_size, void* d_ws, size_t ws_size,
                              hipStream_t stream)
{
  const int* tokens  = (const int*)d_in[0];
  const int* lengths = (const int*)d_in[1];
  const void* emb    = d_in[2];
  const void* Wk[3] = {d_in[3], d_in[6], d_in[9]};
  const void* Wr[3] = {d_in[4], d_in[7], d_in[10]};
  const void* bv[3] = {d_in[5], d_in[8], d_in[11]};
  const void* Wd = d_in[12];
  const void* bd = d_in[13];

  char* ws = (char*)d_ws;
  size_t o = 0;
  u16* Zx0 = (u16*)(ws+o); o += 4096ull*2048*2;     // 16MB
  u16* Zx1 = (u16*)(ws+o); o += 4096ull*2048*2;
  u16* Zx2 = (u16*)(ws+o); o += 4096ull*2048*2;
  u16* xo0 = (u16*)(ws+o); o += 4096ull*512*2;      // 4MB
  u16* xo1 = (u16*)(ws+o); o += 4096ull*512*2;
  u16* xf  = (u16*)(ws+o); o += 65536ull*512*2;     // 64MB
  u16* embH = (u16*)(ws+o); o += 512ull*256*2;
  u16* WkT0 = (u16*)(ws+o); o += 2048ull*256*2;
  u16* WkT1 = (u16*)(ws+o); o += 2048ull*512*2;
  u16* WkT2 = (u16*)(ws+o); o += 2048ull*512*2;
  u16* WrT[3];
  for (int l=0;l<3;++l){ WrT[l] = (u16*)(ws+o); o += 2048ull*512*2; }
  u16* WdT = (u16*)(ws+o); o += 512ull*512*2;
  float* biasP[3];
  for (int l=0;l<3;++l){ biasP[l] = (float*)(ws+o); o += 2048*4; }
  float* bdP = (float*)(ws+o); o += 512*4;
  size_t ctrl0 = o;
  u16*  Hbase = (u16*)(ws+o); o += 3ull*2*65536;    // 3 layers x 2 x 64KB
  float* Cbase = (float*)(ws+o); o += 3ull*64*512*4;
  u32* flagbase = (u32*)(ws+o); o += 1024;
  u32* dtypeflag = (u32*)(ws+o); o += 256;
  size_t need = o;
  if (ws_size < need) return;   // loud failure

  hipMemsetAsync(ws + ctrl0, 0, need - ctrl0, stream);
  hipFuncSetAttribute(reinterpret_cast<const void*>(lstm3),
                      hipFuncAttributeMaxDynamicSharedMemorySize, 147456);

  detect_dtype<<<1,64,0,stream>>>(emb, dtypeflag);
  embconv<<<512,256,0,stream>>>(emb, embH, dtypeflag);
  transpose_bt<<<dim3(64,8) ,256,0,stream>>>(Wk[0], WkT0, 256, 2048, 1, dtypeflag);
  transpose_bt<<<dim3(64,16),256,0,stream>>>(Wk[1], WkT1, 512, 2048, 1, dtypeflag);
  transpose_bt<<<dim3(64,16),256,0,stream>>>(Wk[2], WkT2, 512, 2048, 1, dtypeflag);
  for (int l=0;l<3;++l)
    transpose_bt<<<dim3(64,16),256,0,stream>>>(Wr[l], WrT[l], 512, 2048, 1, dtypeflag);
  transpose_bt<<<dim3(16,16),256,0,stream>>>(Wd, WdT, 512, 512, 0, dtypeflag);
  for (int l=0;l<3;++l) bias_prep<<<8,256,0,stream>>>(bv[l], biasP[l], 2048, 1, dtypeflag);
  bias_prep<<<2,256,0,stream>>>(bd, bdP, 512, 0, dtypeflag);

  for (int d=0; d<18; ++d){
    int act0 = (d <= 15);
    int act1 = (d >= 1 && d <= 16);
    int act2 = (d >= 2);
    gemm3<<<dim3(32,16,3),256,0,stream>>>(xo0, xo1, WkT0, WkT1, WkT2,
                                          biasP[0], biasP[1], biasP[2],
                                          Zx0, Zx1, Zx2,
                                          tokens, embH, d*64, act0, act1, act2);
    lstm3<<<96,256,147456,stream>>>(Zx0, Zx1, Zx2, WrT[0], WrT[1], WrT[2],
                                    lengths, xo0, xo1, xf, Hbase, Cbase, flagbase, d);
  }
  gemm_bt<<<dim3(512,4),256,0,stream>>>(xf, WdT, bdP, d_out, 65536, 512, 512, dtypeflag);
}

// Round 5
// 9276.601 us; speedup vs baseline: 3.4036x; 1.2319x over previous
//
#include <hip/hip_runtime.h>
#include <stdint.h>

typedef unsigned short u16;
typedef unsigned int   u32;
typedef unsigned long long u64;
typedef _Float16 half8 __attribute__((ext_vector_type(8)));
typedef __attribute__((ext_vector_type(4))) float f32x4;

#define DEV static __device__ __forceinline__

DEV float bf2f(u16 u){ union{u32 i; float f;} v; v.i=((u32)u)<<16; return v.f; }
DEV u16 f2bf(float f){ u32 x=__float_as_uint(f); return (u16)((x + 0x7FFFu + ((x>>16)&1u))>>16); }
DEV u16 f2hu(float f){ _Float16 h = (_Float16)f; return *(u16*)&h; }
DEV float hu2f(u16 u){ _Float16 h = *(_Float16*)&u; return (float)h; }
DEV float sigm(float x){ return 1.0f/(1.0f+__expf(-x)); }
DEV float tanhr(float x){ float a=fabsf(x); float e=__expf(-2.0f*a); float t=(1.0f-e)/(1.0f+e); return x<0.0f? -t:t; }

typedef const __attribute__((address_space(1))) u32 gu32;
typedef __attribute__((address_space(3))) u32 lu32;
DEV void gload16(const void* g, void* l){
  __builtin_amdgcn_global_load_lds((gu32*)g, (lu32*)l, 16, 0, 0);
}
// coherent 2B store (write-through to coherence point)
DEV void gstore2c(void* p, u16 v){
  asm volatile("global_store_short %0, %1, off sc0 sc1" : : "v"(p), "v"((u32)v) : "memory");
}

DEV u16 ld_h(const void* p, size_t i, int isbf){
  float f = isbf ? bf2f(((const u16*)p)[i]) : ((const float*)p)[i];
  return f2hu(f);
}

// -------- dtype detector: bf16 exponent-band statistics --------
__global__ void detect_dtype(const void* emb, u32* flag)
{
  const u16* p = (const u16*)emb;
  int i = threadIdx.x;
  u32 e0 = (p[i]    >> 7) & 0xFF;
  u32 e1 = (p[i+64] >> 7) & 0xFF;
  unsigned long long b0 = __ballot(e0 >= 0x60 && e0 <= 0x7E);
  unsigned long long b1 = __ballot(e1 >= 0x60 && e1 <= 0x7E);
  if (i == 0) *flag = (__popcll(b0) + __popcll(b1) > 96) ? 1u : 0u;
}

// -------- emb table -> fp16 (512x256) --------
__global__ __launch_bounds__(256) void embconv(const void* __restrict__ emb, u16* __restrict__ embH,
                                               const u32* __restrict__ flag)
{
  const int isbf = *flag;
  int i = blockIdx.x*256 + threadIdx.x;
  embH[i] = ld_h(emb, i, isbf);
}

// ------------- weight transpose (+ gate interleave): out[n'][k] = fp16(in[k][n]) -------------
__global__ __launch_bounds__(256) void transpose_bt(const void* __restrict__ in,
                                                    u16* __restrict__ out,
                                                    int K, int N, int perm,
                                                    const u32* __restrict__ flag)
{
  const int isbf = *flag;
  __shared__ u16 t[32][33];
  int nb = blockIdx.x*32, kb = blockIdx.y*32;
  int tx = threadIdx.x & 31, ty = threadIdx.x >> 5;   // 32 x 8
  #pragma unroll
  for (int i=0;i<4;++i){
    int kl = ty + i*8;
    t[kl][tx] = ld_h(in, (size_t)(kb+kl)*N + nb + tx, isbf);
  }
  __syncthreads();
  #pragma unroll
  for (int i=0;i<4;++i){
    int nl = ty + i*8;
    int n = nb + nl;
    int np = perm ? ((n & 511)*4 + (n >> 9)) : n;
    out[(size_t)np*K + kb + tx] = t[tx][nl];
  }
}

__global__ __launch_bounds__(256) void bias_prep(const void* __restrict__ in, float* __restrict__ out,
                                                 int N, int perm, const u32* __restrict__ flag)
{
  const int isbf = *flag;
  int n = blockIdx.x*256 + threadIdx.x;
  if (n < N){
    int np = perm ? ((n & 511)*4 + (n >> 9)) : n;
    out[np] = isbf ? bf2f(((const u16*)in)[n]) : ((const float*)in)[n];
  }
}

// ---------------- batched chunk GEMM (swapped operands): Zq[lt][u'][b] = packed 4-gate quads ----------------
// z=0: A gathered from embH via tokens (K=256). z=1,2: A = xo_prev chunk (K=512).
__global__ __launch_bounds__(256) void gemm3(
    const u16* __restrict__ A1, const u16* __restrict__ A2,
    const u16* __restrict__ BT0, const u16* __restrict__ BT1, const u16* __restrict__ BT2,
    const float* __restrict__ b0p, const float* __restrict__ b1p, const float* __restrict__ b2p,
    u16* __restrict__ C0, u16* __restrict__ C1, u16* __restrict__ C2,
    const int* __restrict__ tok, const u16* __restrict__ embH, int t0g,
    int act0, int act1, int act2)
{
  const int z = blockIdx.z;
  if (z==0 && !act0) return;
  if (z==1 && !act1) return;
  if (z==2 && !act2) return;
  const int K = (z==0) ? 256 : 512;
  const u16* BT = z==0?BT0 : z==1?BT1 : BT2;
  const float* bias = z==0?b0p : z==1?b1p : b2p;
  u16* C = z==0?C0 : z==1?C1 : C2;

  __shared__ u16 As[128*32];
  __shared__ u16 Bs[128*32];
  const int tid = threadIdx.x, lane = tid & 63, wid = tid >> 6;
  const int wr = wid >> 1, wc = wid & 1;
  const int m0 = blockIdx.x*128, n0 = blockIdx.y*128;
  const int r  = tid >> 2;
  const int ce = (tid & 3)*8;
  const u16 *a0, *a1;
  if (z == 0){
    int r0 = m0 + r;     int tt = t0g + (r0>>6); int bb = r0 & 63;
    a0 = embH + (size_t)tok[bb*1024 + tt]*256 + ce;
    int r1 = m0 + 64 + r; tt = t0g + (r1>>6); bb = r1 & 63;
    a1 = embH + (size_t)tok[bb*1024 + tt]*256 + ce;
  } else {
    const u16* A = (z==1) ? A1 : A2;
    a0 = A + (size_t)(m0 + r)*512 + ce;
    a1 = A + (size_t)(m0 + 64 + r)*512 + ce;
  }
  const u16* bp0 = BT + (size_t)(n0 + r)*K + ce;
  const u16* bp1 = BT + (size_t)(n0 + 64 + r)*K + ce;
  char* asw0 = (char*)As + (wid<<10);
  char* asw1 = (char*)As + 4096 + (wid<<10);
  char* bsw0 = (char*)Bs + (wid<<10);
  char* bsw1 = (char*)Bs + 4096 + (wid<<10);

  f32x4 acc[4][4];
  #pragma unroll
  for (int i=0;i<4;++i)
    #pragma unroll
    for (int j=0;j<4;++j) acc[i][j] = (f32x4){0.f,0.f,0.f,0.f};

  const int koff = (lane>>4)*8;
  for (int k0 = 0; k0 < K; k0 += 32){
    __syncthreads();
    gload16(a0 + k0, asw0);
    gload16(a1 + k0, asw1);
    gload16(bp0 + k0, bsw0);
    gload16(bp1 + k0, bsw1);
    __syncthreads();
    half8 af[4], bf[4];
    #pragma unroll
    for (int mt=0;mt<4;++mt) af[mt] = *(const half8*)(As + (wr*64 + mt*16 + (lane&15))*32 + koff);
    #pragma unroll
    for (int nt=0;nt<4;++nt) bf[nt] = *(const half8*)(Bs + (wc*64 + nt*16 + (lane&15))*32 + koff);
    // swapped: D rows = n' (register dim j -> gate), D cols = m (lane dim)
    #pragma unroll
    for (int mt=0;mt<4;++mt)
      #pragma unroll
      for (int nt=0;nt<4;++nt)
        acc[mt][nt] = __builtin_amdgcn_mfma_f32_16x16x32_f16(bf[nt], af[mt], acc[mt][nt], 0,0,0);
  }
  #pragma unroll
  for (int mt=0;mt<4;++mt){
    int m = m0 + wr*64 + mt*16 + (lane&15);
    int ltl = m >> 6, b = m & 63;
    #pragma unroll
    for (int nt=0;nt<4;++nt){
      int u = ((n0 + wc*64 + nt*16) >> 2) + (lane>>4);
      float4 bq = *(const float4*)(bias + u*4);
      u16 qo[4];
      qo[0] = f2hu(acc[mt][nt][0] + bq.x);
      qo[1] = f2hu(acc[mt][nt][1] + bq.y);
      qo[2] = f2hu(acc[mt][nt][2] + bq.z);
      qo[3] = f2hu(acc[mt][nt][3] + bq.w);
      ((uint2*)C)[(size_t)(ltl*512 + u)*64 + b] = *(uint2*)qo;
    }
  }
}

// ---------------- final logits GEMM (K=512, output permute t-major -> (B,T), dtype per flag) --------
__global__ __launch_bounds__(256) void gemm_bt(const u16* __restrict__ A, const u16* __restrict__ BT,
                                               const float* __restrict__ bias, void* __restrict__ C,
                                               int M, int N, int K, const u32* __restrict__ flag)
{
  __shared__ u16 As[128*32];
  __shared__ u16 Bs[128*32];
  const int tid = threadIdx.x, lane = tid & 63, wid = tid >> 6;
  const int wr = wid >> 1, wc = wid & 1;
  const int m0 = blockIdx.x*128, n0 = blockIdx.y*128;
  const int r  = tid >> 2;
  const int ce = (tid & 3)*8;
  const u16* a0 = A  + (size_t)(m0 + r)*K + ce;
  const u16* a1 = A  + (size_t)(m0 + 64 + r)*K + ce;
  const u16* b0 = BT + (size_t)(n0 + r)*K + ce;
  const u16* b1 = BT + (size_t)(n0 + 64 + r)*K + ce;
  char* asw0 = (char*)As + (wid<<10);
  char* asw1 = (char*)As + 4096 + (wid<<10);
  char* bsw0 = (char*)Bs + (wid<<10);
  char* bsw1 = (char*)Bs + 4096 + (wid<<10);

  f32x4 acc[4][4];
  #pragma unroll
  for (int i=0;i<4;++i)
    #pragma unroll
    for (int j=0;j<4;++j) acc[i][j] = (f32x4){0.f,0.f,0.f,0.f};

  const int koff = (lane>>4)*8;
  for (int k0 = 0; k0 < K; k0 += 32){
    __syncthreads();
    gload16(a0 + k0, asw0);
    gload16(a1 + k0, asw1);
    gload16(b0 + k0, bsw0);
    gload16(b1 + k0, bsw1);
    __syncthreads();
    half8 af[4], bf[4];
    #pragma unroll
    for (int mt=0;mt<4;++mt) af[mt] = *(const half8*)(As + (wr*64 + mt*16 + (lane&15))*32 + koff);
    #pragma unroll
    for (int nt=0;nt<4;++nt) bf[nt] = *(const half8*)(Bs + (wc*64 + nt*16 + (lane&15))*32 + koff);
    #pragma unroll
    for (int mt=0;mt<4;++mt)
      #pragma unroll
      for (int nt=0;nt<4;++nt)
        acc[mt][nt] = __builtin_amdgcn_mfma_f32_16x16x32_f16(af[mt], bf[nt], acc[mt][nt], 0,0,0);
  }
  const int wrf32 = (*flag == 0);
  #pragma unroll
  for (int mt=0;mt<4;++mt){
    #pragma unroll
    for (int nt=0;nt<4;++nt){
      int col = n0 + wc*64 + nt*16 + (lane&15);
      float bv = bias[col];
      #pragma unroll
      for (int j=0;j<4;++j){
        int row = m0 + wr*64 + mt*16 + ((lane>>4)<<2) + j;
        int orow = ((row & 63) << 10) | (row >> 6);
        float v = acc[mt][nt][j] + bv;
        if (wrf32) ((float*)C)[(size_t)orow*N + col] = v;
        else       ((u16*)C)[(size_t)orow*N + col] = f2bf(v);
      }
    }
  }
}

// ---------------- fused recurrence: 192 WGs = 3 layers x (4 batch-groups x 16 u-WGs) ----------------
// WG (layer, g, i): owns batch rows g*16..+16, u's i*32..+32 (gate-cols i*128..+128).
// Swapped MFMA: lane's 4 acc registers = the 4 gates of one (b,u). Wr in registers.
// H exchange: 16KB staged per step via coherent u64 atomic loads; h written via
// coherent 2B stores. Sync: per-wave atomic-add counters, post-after-read protocol.
__global__ __launch_bounds__(256,1) void lstm3(
    const uint2* __restrict__ Zq0, const uint2* __restrict__ Zq1, const uint2* __restrict__ Zq2,
    const u16* __restrict__ Wr0T, const u16* __restrict__ Wr1T, const u16* __restrict__ Wr2T,
    const int* __restrict__ lengths,
    u16* __restrict__ xo0, u16* __restrict__ xo1, u16* __restrict__ xf,
    u16* Hbase, float* Cbase, u32* flagbase, int d)
{
  __shared__ char Hs[16384];          // 16 rows x 1KB, 16B-block XOR swizzle
  const int tid = threadIdx.x, lane = tid & 63, w = tid >> 6;
  const int layer = blockIdx.x >> 6;
  const int sub = blockIdx.x & 63;
  const int g = sub >> 4, i = sub & 15;
  const int c = d - layer;
  if (c < 0 || c > 15) return;
  const int t0 = c * 64;

  const uint2* Zq = layer==0?Zq0 : layer==1?Zq1 : Zq2;
  const u16* WrT  = layer==0?Wr0T : layer==1?Wr1T : Wr2T;
  u16* H0 = Hbase + (size_t)layer*65536;     // elements; 2 bufs x 32768
  u16* H1 = H0 + 32768;
  float* Cg = Cbase + (size_t)layer*32768;
  u32* flags = flagbase + (layer*4 + g)*16;

  const int q = lane >> 4, r15 = lane & 15, rsw = r15 & 7;
  const int bglob = g*16 + r15;
  const int mylen = lengths[bglob];
  const int u0 = i*32 + (w*2+0)*4 + q;
  const int u1 = i*32 + (w*2+1)*4 + q;

  // Wr slice -> registers: wreg[mt][kk] = WrT[i*128 + (w*2+mt)*16 + r15][kk*32 + q*8 ..]
  half8 wreg[2][16];
  #pragma unroll
  for (int mt=0; mt<2; ++mt){
    const u16* wsrc = WrT + (size_t)(i*128 + (w*2+mt)*16 + r15)*512 + q*8;
    #pragma unroll
    for (int kk=0; kk<16; ++kk)
      wreg[mt][kk] = *(const half8*)(wsrc + kk*32);
  }
  float c0 = Cg[bglob*512 + u0];
  float c1 = Cg[bglob*512 + u1];

  for (int lt = 0; lt < 64; ++lt){
    const int t = t0 + lt;
    const u16* Hcur = (t & 1) ? H1 : H0;
    u16* Hnxt = (t & 1) ? H0 : H1;

    // Zx gate quads (written by previous dispatch's gemm3 — no flag dependency)
    uint2 zqa = Zq[(size_t)(lt*512 + u0)*64 + bglob];
    uint2 zqb = Zq[(size_t)(lt*512 + u1)*64 + bglob];

    // ---- all-wave parallel poll: 16 producers posted step t (counter = 4t) ----
    const u32 target = 4u*(u32)t;
    if (lane < 16 && t > 0){
      while (__hip_atomic_load(&flags[lane], __ATOMIC_RELAXED, __HIP_MEMORY_SCOPE_AGENT) < target)
        __builtin_amdgcn_s_sleep(4);
    }

    // ---- stage H (16 rows x 1KB) via coherent u64 loads -> swizzled LDS ----
    {
      u64 hv[8];
      #pragma unroll
      for (int jj=0;jj<4;++jj){
        int ch = tid + 256*jj;                       // 16B chunk id
        const u64* src = (const u64*)(Hcur + (size_t)(g*16 + (ch>>6))*512 + (ch & 63)*8);
        hv[2*jj]   = __hip_atomic_load(src,   __ATOMIC_RELAXED, __HIP_MEMORY_SCOPE_AGENT);
        hv[2*jj+1] = __hip_atomic_load(src+1, __ATOMIC_RELAXED, __HIP_MEMORY_SCOPE_AGENT);
      }
      #pragma unroll
      for (int jj=0;jj<4;++jj){
        int ch = tid + 256*jj;
        int row = ch>>6, blk = ch & 63;
        uint4 v;
        v.x = (u32)hv[2*jj];   v.y = (u32)(hv[2*jj]>>32);
        v.z = (u32)hv[2*jj+1]; v.w = (u32)(hv[2*jj+1]>>32);
        *(uint4*)(Hs + row*1024 + ((blk ^ (row & 7))<<4)) = v;
      }
    }
    __syncthreads();

    // ---- Z^T = Wr-slice (regs) x H (LDS): lane = (b, u-part), regs = 4 gates ----
    f32x4 acc0 = {0.f,0.f,0.f,0.f}, acc1 = {0.f,0.f,0.f,0.f};
    #pragma unroll
    for (int kk=0;kk<16;++kk){
      half8 hf = *(const half8*)(Hs + r15*1024 + (((kk*4 + q) ^ rsw)<<4));
      acc0 = __builtin_amdgcn_mfma_f32_16x16x32_f16(wreg[0][kk], hf, acc0, 0,0,0);
      acc1 = __builtin_amdgcn_mfma_f32_16x16x32_f16(wreg[1][kk], hf, acc1, 0,0,0);
    }

    // ---- gates fully in-register ----
    const bool live = t < mylen;
    u16 hst0, hst1, xv0, xv1;
    {
      float zi = hu2f((u16)zqa.x)        + acc0[0];
      float zf = hu2f((u16)(zqa.x>>16))  + acc0[1];
      float zg = hu2f((u16)zqa.y)        + acc0[2];
      float zo = hu2f((u16)(zqa.y>>16))  + acc0[3];
      float ii = sigm(zi), ff = sigm(zf), gg = tanhr(zg), oo = sigm(zo);
      float cn = ff*c0 + ii*gg;
      float hn = oo*tanhr(cn);
      c0 = live ? cn : c0;
      int ub = u0*2;
      float hold = hu2f(*(const u16*)(Hs + r15*1024 + (((ub>>4) ^ rsw)<<4) + (ub & 15)));
      hst0 = f2hu(live ? hn : hold);
      xv0  = f2hu(live ? hn : 0.f);
    }
    {
      float zi = hu2f((u16)zqb.x)        + acc1[0];
      float zf = hu2f((u16)(zqb.x>>16))  + acc1[1];
      float zg = hu2f((u16)zqb.y)        + acc1[2];
      float zo = hu2f((u16)(zqb.y>>16))  + acc1[3];
      float ii = sigm(zi), ff = sigm(zf), gg = tanhr(zg), oo = sigm(zo);
      float cn = ff*c1 + ii*gg;
      float hn = oo*tanhr(cn);
      c1 = live ? cn : c1;
      int ub = u1*2;
      float hold = hu2f(*(const u16*)(Hs + r15*1024 + (((ub>>4) ^ rsw)<<4) + (ub & 15)));
      hst1 = f2hu(live ? hn : hold);
      xv1  = f2hu(live ? hn : 0.f);
    }
    // coherent h stores first (asm), then plain xout stores, then drain leaving xouts in flight
    gstore2c(Hnxt + (size_t)bglob*512 + u0, hst0);
    gstore2c(Hnxt + (size_t)bglob*512 + u1, hst1);
    if (layer == 2){
      xf[((size_t)t*64 + bglob)*512 + u0] = xv0;
      xf[((size_t)t*64 + bglob)*512 + u1] = xv1;
    } else {
      u16* xo = layer ? xo1 : xo0;
      xo[((size_t)lt*64 + bglob)*512 + u0] = xv0;
      xo[((size_t)lt*64 + bglob)*512 + u1] = xv1;
    }
    asm volatile("s_waitcnt vmcnt(2)" ::: "memory");
    if (lane == 0)
      __hip_atomic_fetch_add(&flags[i], 1u, __ATOMIC_RELAXED, __HIP_MEMORY_SCOPE_AGENT);
    // no barrier: post-after-read counter protocol protects Hs and H buffers
  }
  Cg[bglob*512 + u0] = c0;
  Cg[bglob*512 + u1] = c1;
}

// ---------------------------------- host ----------------------------------
extern "C" void kernel_launch(void* const* d_in, const int* in_sizes, int n_in,
                              void* d_out, int out_size, void* d_ws, size_t ws_size,
                              hipStream_t stream)
{
  const int* tokens  = (const int*)d_in[0];
  const int* lengths = (const int*)d_in[1];
  const void* emb    = d_in[2];
  const void* Wk[3] = {d_in[3], d_in[6], d_in[9]};
  const void* Wr[3] = {d_in[4], d_in[7], d_in[10]};
  const void* bv[3] = {d_in[5], d_in[8], d_in[11]};
  const void* Wd = d_in[12];
  const void* bd = d_in[13];

  char* ws = (char*)d_ws;
  size_t o = 0;
  u16* Zq0 = (u16*)(ws+o); o += 16777216;           // [64][512][64] uint2 = 16MB each
  u16* Zq1 = (u16*)(ws+o); o += 16777216;
  u16* Zq2 = (u16*)(ws+o); o += 16777216;
  u16* xo0 = (u16*)(ws+o); o += 4096ull*512*2;      // 4MB
  u16* xo1 = (u16*)(ws+o); o += 4096ull*512*2;
  u16* xf  = (u16*)(ws+o); o += 65536ull*512*2;     // 64MB
  u16* embH = (u16*)(ws+o); o += 512ull*256*2;
  u16* WkT0 = (u16*)(ws+o); o += 2048ull*256*2;
  u16* WkT1 = (u16*)(ws+o); o += 2048ull*512*2;
  u16* WkT2 = (u16*)(ws+o); o += 2048ull*512*2;
  u16* WrT[3];
  for (int l=0;l<3;++l){ WrT[l] = (u16*)(ws+o); o += 2048ull*512*2; }
  u16* WdT = (u16*)(ws+o); o += 512ull*512*2;
  float* biasP[3];
  for (int l=0;l<3;++l){ biasP[l] = (float*)(ws+o); o += 2048*4; }
  float* bdP = (float*)(ws+o); o += 512*4;
  size_t ctrl0 = o;
  u16*  Hbase = (u16*)(ws+o); o += 3ull*2*65536;    // 3 layers x 2 bufs x 64KB
  float* Cbase = (float*)(ws+o); o += 3ull*64*512*4;
  u32* flagbase = (u32*)(ws+o); o += 1024;          // 3*4*16 counters
  u32* dtypeflag = (u32*)(ws+o); o += 256;
  size_t need = o;
  if (ws_size < need) return;   // loud failure

  hipMemsetAsync(ws + ctrl0, 0, need - ctrl0, stream);

  detect_dtype<<<1,64,0,stream>>>(emb, dtypeflag);
  embconv<<<512,256,0,stream>>>(emb, embH, dtypeflag);
  transpose_bt<<<dim3(64,8) ,256,0,stream>>>(Wk[0], WkT0, 256, 2048, 1, dtypeflag);
  transpose_bt<<<dim3(64,16),256,0,stream>>>(Wk[1], WkT1, 512, 2048, 1, dtypeflag);
  transpose_bt<<<dim3(64,16),256,0,stream>>>(Wk[2], WkT2, 512, 2048, 1, dtypeflag);
  for (int l=0;l<3;++l)
    transpose_bt<<<dim3(64,16),256,0,stream>>>(Wr[l], WrT[l], 512, 2048, 1, dtypeflag);
  transpose_bt<<<dim3(16,16),256,0,stream>>>(Wd, WdT, 512, 512, 0, dtypeflag);
  for (int l=0;l<3;++l) bias_prep<<<8,256,0,stream>>>(bv[l], biasP[l], 2048, 1, dtypeflag);
  bias_prep<<<2,256,0,stream>>>(bd, bdP, 512, 0, dtypeflag);

  for (int d=0; d<18; ++d){
    int act0 = (d <= 15);
    int act1 = (d >= 1 && d <= 16);
    int act2 = (d >= 2);
    gemm3<<<dim3(32,16,3),256,0,stream>>>(xo0, xo1, WkT0, WkT1, WkT2,
                                          biasP[0], biasP[1], biasP[2],
                                          Zq0, Zq1, Zq2,
                                          tokens, embH, d*64, act0, act1, act2);
    lstm3<<<192,256,0,stream>>>((const uint2*)Zq0, (const uint2*)Zq1, (const uint2*)Zq2,
                                WrT[0], WrT[1], WrT[2],
                                lengths, xo0, xo1, xf, Hbase, Cbase, flagbase, d);
  }
  gemm_bt<<<dim3(512,4),256,0,stream>>>(xf, WdT, bdP, d_out, 65536, 512, 512, dtypeflag);
}

// Round 6
// 5206.258 us; speedup vs baseline: 6.0647x; 1.7818x over previous
//
#include <hip/hip_runtime.h>
#include <stdint.h>

typedef unsigned short u16;
typedef unsigned int   u32;
typedef unsigned long long u64;
typedef _Float16 half8 __attribute__((ext_vector_type(8)));
typedef __attribute__((ext_vector_type(4))) float f32x4;

#define DEV static __device__ __forceinline__

DEV float bf2f(u16 u){ union{u32 i; float f;} v; v.i=((u32)u)<<16; return v.f; }
DEV u16 f2bf(float f){ u32 x=__float_as_uint(f); return (u16)((x + 0x7FFFu + ((x>>16)&1u))>>16); }
DEV u16 f2hu(float f){ _Float16 h = (_Float16)f; return *(u16*)&h; }
DEV float hu2f(u16 u){ _Float16 h = *(_Float16*)&u; return (float)h; }
DEV float sigm(float x){ return 1.0f/(1.0f+__expf(-x)); }
DEV float tanhr(float x){ float a=fabsf(x); float e=__expf(-2.0f*a); float t=(1.0f-e)/(1.0f+e); return x<0.0f? -t:t; }

typedef const __attribute__((address_space(1))) u32 gu32;
typedef __attribute__((address_space(3))) u32 lu32;
DEV void gload16(const void* g, void* l){
  __builtin_amdgcn_global_load_lds((gu32*)g, (lu32*)l, 16, 0, 0);
}
// coherent 4B store (write-through to coherence point), fire-and-forget
DEV void gstore4c(void* p, u32 v){
  asm volatile("global_store_dword %0, %1, off sc0 sc1" : : "v"(p), "v"(v) : "memory");
}

DEV u16 ld_h(const void* p, size_t i, int isbf){
  float f = isbf ? bf2f(((const u16*)p)[i]) : ((const float*)p)[i];
  return f2hu(f);
}

// -------- dtype detector: bf16 exponent-band statistics --------
__global__ void detect_dtype(const void* emb, u32* flag)
{
  const u16* p = (const u16*)emb;
  int i = threadIdx.x;
  u32 e0 = (p[i]    >> 7) & 0xFF;
  u32 e1 = (p[i+64] >> 7) & 0xFF;
  unsigned long long b0 = __ballot(e0 >= 0x60 && e0 <= 0x7E);
  unsigned long long b1 = __ballot(e1 >= 0x60 && e1 <= 0x7E);
  if (i == 0) *flag = (__popcll(b0) + __popcll(b1) > 96) ? 1u : 0u;
}

// -------- emb table -> fp16 (512x256) --------
__global__ __launch_bounds__(256) void embconv(const void* __restrict__ emb, u16* __restrict__ embH,
                                               const u32* __restrict__ flag)
{
  const int isbf = *flag;
  int i = blockIdx.x*256 + threadIdx.x;
  embH[i] = ld_h(emb, i, isbf);
}

// ------------- weight transpose (+ gate interleave): out[n'][k] = fp16(in[k][n]) -------------
__global__ __launch_bounds__(256) void transpose_bt(const void* __restrict__ in,
                                                    u16* __restrict__ out,
                                                    int K, int N, int perm,
                                                    const u32* __restrict__ flag)
{
  const int isbf = *flag;
  __shared__ u16 t[32][33];
  int nb = blockIdx.x*32, kb = blockIdx.y*32;
  int tx = threadIdx.x & 31, ty = threadIdx.x >> 5;   // 32 x 8
  #pragma unroll
  for (int i=0;i<4;++i){
    int kl = ty + i*8;
    t[kl][tx] = ld_h(in, (size_t)(kb+kl)*N + nb + tx, isbf);
  }
  __syncthreads();
  #pragma unroll
  for (int i=0;i<4;++i){
    int nl = ty + i*8;
    int n = nb + nl;
    int np = perm ? ((n & 511)*4 + (n >> 9)) : n;
    out[(size_t)np*K + kb + tx] = t[tx][nl];
  }
}

__global__ __launch_bounds__(256) void bias_prep(const void* __restrict__ in, float* __restrict__ out,
                                                 int N, int perm, const u32* __restrict__ flag)
{
  const int isbf = *flag;
  int n = blockIdx.x*256 + threadIdx.x;
  if (n < N){
    int np = perm ? ((n & 511)*4 + (n >> 9)) : n;
    out[np] = isbf ? bf2f(((const u16*)in)[n]) : ((const float*)in)[n];
  }
}

// ---------------- batched chunk GEMM (swapped operands): Zq[lt][u'][b] = packed 4-gate quads ----------------
// z=0: A gathered from embH via tokens (K=256). z=1,2: A = xo_prev chunk (K=512).
__global__ __launch_bounds__(256) void gemm3(
    const u16* __restrict__ A1, const u16* __restrict__ A2,
    const u16* __restrict__ BT0, const u16* __restrict__ BT1, const u16* __restrict__ BT2,
    const float* __restrict__ b0p, const float* __restrict__ b1p, const float* __restrict__ b2p,
    u16* __restrict__ C0, u16* __restrict__ C1, u16* __restrict__ C2,
    const int* __restrict__ tok, const u16* __restrict__ embH, int t0g,
    int act0, int act1, int act2)
{
  const int z = blockIdx.z;
  if (z==0 && !act0) return;
  if (z==1 && !act1) return;
  if (z==2 && !act2) return;
  const int K = (z==0) ? 256 : 512;
  const u16* BT = z==0?BT0 : z==1?BT1 : BT2;
  const float* bias = z==0?b0p : z==1?b1p : b2p;
  u16* C = z==0?C0 : z==1?C1 : C2;

  __shared__ u16 As[128*32];
  __shared__ u16 Bs[128*32];
  const int tid = threadIdx.x, lane = tid & 63, wid = tid >> 6;
  const int wr = wid >> 1, wc = wid & 1;
  const int m0 = blockIdx.x*128, n0 = blockIdx.y*128;
  const int r  = tid >> 2;
  const int ce = (tid & 3)*8;
  const u16 *a0, *a1;
  if (z == 0){
    int r0 = m0 + r;     int tt = t0g + (r0>>6); int bb = r0 & 63;
    a0 = embH + (size_t)tok[bb*1024 + tt]*256 + ce;
    int r1 = m0 + 64 + r; tt = t0g + (r1>>6); bb = r1 & 63;
    a1 = embH + (size_t)tok[bb*1024 + tt]*256 + ce;
  } else {
    const u16* A = (z==1) ? A1 : A2;
    a0 = A + (size_t)(m0 + r)*512 + ce;
    a1 = A + (size_t)(m0 + 64 + r)*512 + ce;
  }
  const u16* bp0 = BT + (size_t)(n0 + r)*K + ce;
  const u16* bp1 = BT + (size_t)(n0 + 64 + r)*K + ce;
  char* asw0 = (char*)As + (wid<<10);
  char* asw1 = (char*)As + 4096 + (wid<<10);
  char* bsw0 = (char*)Bs + (wid<<10);
  char* bsw1 = (char*)Bs + 4096 + (wid<<10);

  f32x4 acc[4][4];
  #pragma unroll
  for (int i=0;i<4;++i)
    #pragma unroll
    for (int j=0;j<4;++j) acc[i][j] = (f32x4){0.f,0.f,0.f,0.f};

  const int koff = (lane>>4)*8;
  for (int k0 = 0; k0 < K; k0 += 32){
    __syncthreads();
    gload16(a0 + k0, asw0);
    gload16(a1 + k0, asw1);
    gload16(bp0 + k0, bsw0);
    gload16(bp1 + k0, bsw1);
    __syncthreads();
    half8 af[4], bf[4];
    #pragma unroll
    for (int mt=0;mt<4;++mt) af[mt] = *(const half8*)(As + (wr*64 + mt*16 + (lane&15))*32 + koff);
    #pragma unroll
    for (int nt=0;nt<4;++nt) bf[nt] = *(const half8*)(Bs + (wc*64 + nt*16 + (lane&15))*32 + koff);
    // swapped: D rows = n' (register dim j -> gate), D cols = m (lane dim)
    #pragma unroll
    for (int mt=0;mt<4;++mt)
      #pragma unroll
      for (int nt=0;nt<4;++nt)
        acc[mt][nt] = __builtin_amdgcn_mfma_f32_16x16x32_f16(bf[nt], af[mt], acc[mt][nt], 0,0,0);
  }
  #pragma unroll
  for (int mt=0;mt<4;++mt){
    int m = m0 + wr*64 + mt*16 + (lane&15);
    int ltl = m >> 6, b = m & 63;
    #pragma unroll
    for (int nt=0;nt<4;++nt){
      int u = ((n0 + wc*64 + nt*16) >> 2) + (lane>>4);
      float4 bq = *(const float4*)(bias + u*4);
      u16 qo[4];
      qo[0] = f2hu(acc[mt][nt][0] + bq.x);
      qo[1] = f2hu(acc[mt][nt][1] + bq.y);
      qo[2] = f2hu(acc[mt][nt][2] + bq.z);
      qo[3] = f2hu(acc[mt][nt][3] + bq.w);
      ((uint2*)C)[(size_t)(ltl*512 + u)*64 + b] = *(uint2*)qo;
    }
  }
}

// ---------------- final logits GEMM (K=512, output permute t-major -> (B,T), dtype per flag) --------
__global__ __launch_bounds__(256) void gemm_bt(const u16* __restrict__ A, const u16* __restrict__ BT,
                                               const float* __restrict__ bias, void* __restrict__ C,
                                               int M, int N, int K, const u32* __restrict__ flag)
{
  __shared__ u16 As[128*32];
  __shared__ u16 Bs[128*32];
  const int tid = threadIdx.x, lane = tid & 63, wid = tid >> 6;
  const int wr = wid >> 1, wc = wid & 1;
  const int m0 = blockIdx.x*128, n0 = blockIdx.y*128;
  const int r  = tid >> 2;
  const int ce = (tid & 3)*8;
  const u16* a0 = A  + (size_t)(m0 + r)*K + ce;
  const u16* a1 = A  + (size_t)(m0 + 64 + r)*K + ce;
  const u16* b0 = BT + (size_t)(n0 + r)*K + ce;
  const u16* b1 = BT + (size_t)(n0 + 64 + r)*K + ce;
  char* asw0 = (char*)As + (wid<<10);
  char* asw1 = (char*)As + 4096 + (wid<<10);
  char* bsw0 = (char*)Bs + (wid<<10);
  char* bsw1 = (char*)Bs + 4096 + (wid<<10);

  f32x4 acc[4][4];
  #pragma unroll
  for (int i=0;i<4;++i)
    #pragma unroll
    for (int j=0;j<4;++j) acc[i][j] = (f32x4){0.f,0.f,0.f,0.f};

  const int koff = (lane>>4)*8;
  for (int k0 = 0; k0 < K; k0 += 32){
    __syncthreads();
    gload16(a0 + k0, asw0);
    gload16(a1 + k0, asw1);
    gload16(b0 + k0, bsw0);
    gload16(b1 + k0, bsw1);
    __syncthreads();
    half8 af[4], bf[4];
    #pragma unroll
    for (int mt=0;mt<4;++mt) af[mt] = *(const half8*)(As + (wr*64 + mt*16 + (lane&15))*32 + koff);
    #pragma unroll
    for (int nt=0;nt<4;++nt) bf[nt] = *(const half8*)(Bs + (wc*64 + nt*16 + (lane&15))*32 + koff);
    #pragma unroll
    for (int mt=0;mt<4;++mt)
      #pragma unroll
      for (int nt=0;nt<4;++nt)
        acc[mt][nt] = __builtin_amdgcn_mfma_f32_16x16x32_f16(af[mt], bf[nt], acc[mt][nt], 0,0,0);
  }
  const int wrf32 = (*flag == 0);
  #pragma unroll
  for (int mt=0;mt<4;++mt){
    #pragma unroll
    for (int nt=0;nt<4;++nt){
      int col = n0 + wc*64 + nt*16 + (lane&15);
      float bv = bias[col];
      #pragma unroll
      for (int j=0;j<4;++j){
        int row = m0 + wr*64 + mt*16 + ((lane>>4)<<2) + j;
        int orow = ((row & 63) << 10) | (row >> 6);
        float v = acc[mt][nt][j] + bv;
        if (wrf32) ((float*)C)[(size_t)orow*N + col] = v;
        else       ((u16*)C)[(size_t)orow*N + col] = f2bf(v);
      }
    }
  }
}

// ---------------- fused recurrence: 192 WGs = 3 layers x (4 batch-groups x 16 u-WGs) ----------------
// Sync = DATA-EMBEDDED TAGS: H entries are u32 (tag<<16)|fp16, double-buffered by step parity.
// Producer: fire-and-forget sc0sc1 stores (no drain, no flags). Consumer: spin on tagged
// u64 coherent loads of its 32B chunks (stale-tracking), extract -> swizzled LDS.
// Safety: tag t+2 (same buffer as t) can only be stored after ALL WGs stored t+1, which
// requires all consumed t -- so equality polling can never miss/deadlock.
__global__ __launch_bounds__(256,1) void lstm3(
    const uint2* __restrict__ Zq0, const uint2* __restrict__ Zq1, const uint2* __restrict__ Zq2,
    const u16* __restrict__ Wr0T, const u16* __restrict__ Wr1T, const u16* __restrict__ Wr2T,
    const int* __restrict__ lengths,
    u16* __restrict__ xo0, u16* __restrict__ xo1, u16* __restrict__ xf,
    u32* Hbase, float* Cbase, int d)
{
  __shared__ char Hs[16384];          // 16 rows x 1KB fp16, 16B-block XOR swizzle
  const int tid = threadIdx.x, lane = tid & 63, w = tid >> 6;
  const int layer = blockIdx.x >> 6;
  const int sub = blockIdx.x & 63;
  const int g = sub >> 4, i = sub & 15;
  const int c = d - layer;
  if (c < 0 || c > 15) return;
  const int t0 = c * 64;

  const uint2* Zq = layer==0?Zq0 : layer==1?Zq1 : Zq2;
  const u16* WrT  = layer==0?Wr0T : layer==1?Wr1T : Wr2T;
  u32* Hb0 = Hbase + (size_t)layer*65536;    // 2 bufs x [64][512] u32
  u32* Hb1 = Hb0 + 32768;
  float* Cg = Cbase + (size_t)layer*32768;

  const int q = lane >> 4, r15 = lane & 15, rsw = r15 & 7;
  const int bglob = g*16 + r15;
  const int mylen = lengths[bglob];
  const int u0 = i*32 + w*8 + q;
  const int u1 = u0 + 4;

  // Wr slice -> registers
  half8 wreg[2][16];
  #pragma unroll
  for (int mt=0; mt<2; ++mt){
    const u16* wsrc = WrT + (size_t)(i*128 + (w*2+mt)*16 + r15)*512 + q*8;
    #pragma unroll
    for (int kk=0; kk<16; ++kk)
      wreg[mt][kk] = *(const half8*)(wsrc + kk*32);
  }
  float c0 = Cg[bglob*512 + u0];
  float c1 = Cg[bglob*512 + u1];

  // staging geometry: 4 chunks/thread, chunk = 8 u32 (32B tagged = 16B fp16)
  int chrow[4], chblk[4];
  #pragma unroll
  for (int jj=0;jj<4;++jj){ int ch = jj*256 + tid; chrow[jj] = ch>>6; chblk[jj] = ch & 63; }

  for (int lt = 0; lt < 64; ++lt){
    const int t = t0 + lt;
    u32* Hcur = (t & 1) ? Hb1 : Hb0;
    u32* Hnxt = (t & 1) ? Hb0 : Hb1;

    // Zx gate quads (plain cached loads, written by previous dispatch's gemm3)
    uint2 zqa = Zq[(size_t)(lt*512 + u0)*64 + bglob];
    uint2 zqb = Zq[(size_t)(lt*512 + u1)*64 + bglob];

    // ---- poll + stage: spin until each chunk's 8 tags == t, then extract -> LDS ----
    {
      const u32 tg = (u32)t;
      u32 pend = 0xF;
      do {
        #pragma unroll
        for (int jj=0;jj<4;++jj) if (pend & (1u<<jj)){
          const u64* src = (const u64*)(Hcur + (size_t)(g*16 + chrow[jj])*512 + chblk[jj]*8);
          u64 a0 = __hip_atomic_load(src+0, __ATOMIC_RELAXED, __HIP_MEMORY_SCOPE_AGENT);
          u64 a1 = __hip_atomic_load(src+1, __ATOMIC_RELAXED, __HIP_MEMORY_SCOPE_AGENT);
          u64 a2 = __hip_atomic_load(src+2, __ATOMIC_RELAXED, __HIP_MEMORY_SCOPE_AGENT);
          u64 a3 = __hip_atomic_load(src+3, __ATOMIC_RELAXED, __HIP_MEMORY_SCOPE_AGENT);
          bool ok = (((u32)a0)>>16)==tg && (((u32)(a0>>32))>>16)==tg
                 && (((u32)a1)>>16)==tg && (((u32)(a1>>32))>>16)==tg
                 && (((u32)a2)>>16)==tg && (((u32)(a2>>32))>>16)==tg
                 && (((u32)a3)>>16)==tg && (((u32)(a3>>32))>>16)==tg;
          if (ok){
            uint4 v;
            v.x = (((u32)a0)&0xFFFFu) | (((u32)(a0>>32))<<16);
            v.y = (((u32)a1)&0xFFFFu) | (((u32)(a1>>32))<<16);
            v.z = (((u32)a2)&0xFFFFu) | (((u32)(a2>>32))<<16);
            v.w = (((u32)a3)&0xFFFFu) | (((u32)(a3>>32))<<16);
            *(uint4*)(Hs + chrow[jj]*1024 + ((chblk[jj] ^ (chrow[jj] & 7))<<4)) = v;
            pend &= ~(1u<<jj);
          }
        }
      } while (pend);
    }
    __syncthreads();

    // ---- Z^T = Wr-slice (regs) x H (LDS): lane = (b, u-part), regs = 4 gates ----
    f32x4 acc0 = {0.f,0.f,0.f,0.f}, acc1 = {0.f,0.f,0.f,0.f};
    #pragma unroll
    for (int kk=0;kk<16;++kk){
      half8 hf = *(const half8*)(Hs + r15*1024 + (((kk*4 + q) ^ rsw)<<4));
      acc0 = __builtin_amdgcn_mfma_f32_16x16x32_f16(wreg[0][kk], hf, acc0, 0,0,0);
      acc1 = __builtin_amdgcn_mfma_f32_16x16x32_f16(wreg[1][kk], hf, acc1, 0,0,0);
    }

    // ---- gates fully in-register ----
    const bool live = t < mylen;
    u16 hst0, hst1, xv0, xv1;
    {
      float zi = hu2f((u16)zqa.x)        + acc0[0];
      float zf = hu2f((u16)(zqa.x>>16))  + acc0[1];
      float zg = hu2f((u16)zqa.y)        + acc0[2];
      float zo = hu2f((u16)(zqa.y>>16))  + acc0[3];
      float ii = sigm(zi), ff = sigm(zf), gg = tanhr(zg), oo = sigm(zo);
      float cn = ff*c0 + ii*gg;
      float hn = oo*tanhr(cn);
      c0 = live ? cn : c0;
      int ub = u0*2;
      float hold = hu2f(*(const u16*)(Hs + r15*1024 + (((ub>>4) ^ rsw)<<4) + (ub & 15)));
      hst0 = f2hu(live ? hn : hold);
      xv0  = f2hu(live ? hn : 0.f);
    }
    {
      float zi = hu2f((u16)zqb.x)        + acc1[0];
      float zf = hu2f((u16)(zqb.x>>16))  + acc1[1];
      float zg = hu2f((u16)zqb.y)        + acc1[2];
      float zo = hu2f((u16)(zqb.y>>16))  + acc1[3];
      float ii = sigm(zi), ff = sigm(zf), gg = tanhr(zg), oo = sigm(zo);
      float cn = ff*c1 + ii*gg;
      float hn = oo*tanhr(cn);
      c1 = live ? cn : c1;
      int ub = u1*2;
      float hold = hu2f(*(const u16*)(Hs + r15*1024 + (((ub>>4) ^ rsw)<<4) + (ub & 15)));
      hst1 = f2hu(live ? hn : hold);
      xv1  = f2hu(live ? hn : 0.f);
    }
    // tagged h stores: fire-and-forget, no drain
    u32 s0 = (((u32)(t+1))<<16) | (u32)hst0;
    u32 s1 = (((u32)(t+1))<<16) | (u32)hst1;
    gstore4c(Hnxt + (size_t)bglob*512 + u0, s0);
    gstore4c(Hnxt + (size_t)bglob*512 + u1, s1);
    if (layer == 2){
      xf[((size_t)t*64 + bglob)*512 + u0] = xv0;
      xf[((size_t)t*64 + bglob)*512 + u1] = xv1;
    } else {
      u16* xo = layer ? xo1 : xo0;
      xo[((size_t)lt*64 + bglob)*512 + u0] = xv0;
      xo[((size_t)lt*64 + bglob)*512 + u1] = xv1;
    }
    __syncthreads();   // protect Hs from next iteration's staging overwrite
  }
  Cg[bglob*512 + u0] = c0;
  Cg[bglob*512 + u1] = c1;
}

// ---------------------------------- host ----------------------------------
extern "C" void kernel_launch(void* const* d_in, const int* in_sizes, int n_in,
                              void* d_out, int out_size, void* d_ws, size_t ws_size,
                              hipStream_t stream)
{
  const int* tokens  = (const int*)d_in[0];
  const int* lengths = (const int*)d_in[1];
  const void* emb    = d_in[2];
  const void* Wk[3] = {d_in[3], d_in[6], d_in[9]};
  const void* Wr[3] = {d_in[4], d_in[7], d_in[10]};
  const void* bv[3] = {d_in[5], d_in[8], d_in[11]};
  const void* Wd = d_in[12];
  const void* bd = d_in[13];

  char* ws = (char*)d_ws;
  size_t o = 0;
  u16* Zq0 = (u16*)(ws+o); o += 16777216;           // [64][512][64] uint2 = 16MB each
  u16* Zq1 = (u16*)(ws+o); o += 16777216;
  u16* Zq2 = (u16*)(ws+o); o += 16777216;
  u16* xo0 = (u16*)(ws+o); o += 4096ull*512*2;      // 4MB
  u16* xo1 = (u16*)(ws+o); o += 4096ull*512*2;
  u16* xf  = (u16*)(ws+o); o += 65536ull*512*2;     // 64MB
  u16* embH = (u16*)(ws+o); o += 512ull*256*2;
  u16* WkT0 = (u16*)(ws+o); o += 2048ull*256*2;
  u16* WkT1 = (u16*)(ws+o); o += 2048ull*512*2;
  u16* WkT2 = (u16*)(ws+o); o += 2048ull*512*2;
  u16* WrT[3];
  for (int l=0;l<3;++l){ WrT[l] = (u16*)(ws+o); o += 2048ull*512*2; }
  u16* WdT = (u16*)(ws+o); o += 512ull*512*2;
  float* biasP[3];
  for (int l=0;l<3;++l){ biasP[l] = (float*)(ws+o); o += 2048*4; }
  float* bdP = (float*)(ws+o); o += 512*4;
  size_t ctrl0 = o;
  u32*  Hbase = (u32*)(ws+o); o += 3ull*65536*4;    // 3 layers x 2 bufs x [64][512] u32 = 768KB
  float* Cbase = (float*)(ws+o); o += 3ull*32768*4; // 384KB
  u32* dtypeflag = (u32*)(ws+o); o += 256;
  size_t need = o;
  if (ws_size < need) return;   // loud failure

  hipMemsetAsync(ws + ctrl0, 0, need - ctrl0, stream);

  detect_dtype<<<1,64,0,stream>>>(emb, dtypeflag);
  embconv<<<512,256,0,stream>>>(emb, embH, dtypeflag);
  transpose_bt<<<dim3(64,8) ,256,0,stream>>>(Wk[0], WkT0, 256, 2048, 1, dtypeflag);
  transpose_bt<<<dim3(64,16),256,0,stream>>>(Wk[1], WkT1, 512, 2048, 1, dtypeflag);
  transpose_bt<<<dim3(64,16),256,0,stream>>>(Wk[2], WkT2, 512, 2048, 1, dtypeflag);
  for (int l=0;l<3;++l)
    transpose_bt<<<dim3(64,16),256,0,stream>>>(Wr[l], WrT[l], 512, 2048, 1, dtypeflag);
  transpose_bt<<<dim3(16,16),256,0,stream>>>(Wd, WdT, 512, 512, 0, dtypeflag);
  for (int l=0;l<3;++l) bias_prep<<<8,256,0,stream>>>(bv[l], biasP[l], 2048, 1, dtypeflag);
  bias_prep<<<2,256,0,stream>>>(bd, bdP, 512, 0, dtypeflag);

  for (int d=0; d<18; ++d){
    int act0 = (d <= 15);
    int act1 = (d >= 1 && d <= 16);
    int act2 = (d >= 2);
    gemm3<<<dim3(32,16,3),256,0,stream>>>(xo0, xo1, WkT0, WkT1, WkT2,
                                          biasP[0], biasP[1], biasP[2],
                                          Zq0, Zq1, Zq2,
                                          tokens, embH, d*64, act0, act1, act2);
    lstm3<<<192,256,0,stream>>>((const uint2*)Zq0, (const uint2*)Zq1, (const uint2*)Zq2,
                                WrT[0], WrT[1], WrT[2],
                                lengths, xo0, xo1, xf, Hbase, Cbase, d);
  }
  gemm_bt<<<dim3(512,4),256,0,stream>>>(xf, WdT, bdP, d_out, 65536, 512, 512, dtypeflag);
}